// Round 2
// baseline (4344.340 us; speedup 1.0000x reference)
//
#include <hip/hip_runtime.h>
#include <hip/hip_bf16.h>
#include <hip/hip_cooperative_groups.h>

namespace cg = cooperative_groups;

#define B_ 128
#define T_ 64
#define H_ 256
#define E_ 256
#define L_ 512
#define V_ 30522
#define EOS_ 2
#define BH_ (B_ * H_)

typedef __attribute__((ext_vector_type(8))) short bf16x8;
typedef __attribute__((ext_vector_type(4))) float f32x4;

__device__ __forceinline__ float4 ld4(const float* p) { return *(const float4*)p; }
__device__ __forceinline__ float dot4(float4 a, float4 b) {
  return a.x * b.x + a.y * b.y + a.z * b.z + a.w * b.w;
}

// ---------------------------------------------------------------------------
// Convert W_out (f32) -> bf16
// ---------------------------------------------------------------------------
__global__ __launch_bounds__(256) void conv_wout(
    const float* __restrict__ W, __hip_bfloat16* __restrict__ out, int total) {
  int i = (blockIdx.x * 256 + threadIdx.x) * 8;
  if (i + 8 <= total) {
    float4 lo = ld4(W + i), hi = ld4(W + i + 4);
    union { bf16x8 v8; __hip_bfloat16 e[8]; } u;
    u.e[0] = __float2bfloat16(lo.x); u.e[1] = __float2bfloat16(lo.y);
    u.e[2] = __float2bfloat16(lo.z); u.e[3] = __float2bfloat16(lo.w);
    u.e[4] = __float2bfloat16(hi.x); u.e[5] = __float2bfloat16(hi.y);
    u.e[6] = __float2bfloat16(hi.z); u.e[7] = __float2bfloat16(hi.w);
    *(bf16x8*)(out + i) = u.v8;
  }
}

// ---------------------------------------------------------------------------
// xg[m][g] = emb[tok(m)] . W_ih0[g] + b_ih0[g] + b_hh0[g],  m = t*128+b
// grid (256, 32): rows rt*32.., cols ct*32..
// ---------------------------------------------------------------------------
__global__ __launch_bounds__(256) void xg_kernel(
    const int* __restrict__ targ, const float* __restrict__ emb,
    const float* __restrict__ W_ih0, const float* __restrict__ b_ih0,
    const float* __restrict__ b_hh0, float* __restrict__ xg) {
  __shared__ float4 ldsX[64][32];
  int tid = threadIdx.x;
  int rt = blockIdx.x, ct = blockIdx.y;
  int t = (rt * 32) >> 7;  // same for whole block (32 | 128)
  {
    int r = tid & 31;
    int b = (rt & 3) * 32 + r;
    int tok = (t == 0) ? EOS_ : targ[b * T_ + t - 1];
    const float* src = emb + (size_t)tok * E_;
    #pragma unroll
    for (int j = 0; j < 8; ++j) {
      int c = (tid >> 5) + 8 * j;
      ldsX[c][r] = ld4(src + c * 4);
    }
  }
  __syncthreads();
  int r_local = tid & 31;
  int c_grp = tid >> 5;
  float acc[4];
  const float* w[4];
  int g[4];
  #pragma unroll
  for (int q = 0; q < 4; ++q) {
    g[q] = ct * 32 + c_grp + 8 * q;
    acc[q] = b_ih0[g[q]] + b_hh0[g[q]];
    w[q] = W_ih0 + (size_t)g[q] * E_;
  }
  #pragma unroll 2
  for (int j = 0; j < 64; ++j) {
    float4 xv = ldsX[j][r_local];
    #pragma unroll
    for (int q = 0; q < 4; ++q) acc[q] += dot4(xv, ld4(w[q] + j * 4));
  }
  int m = rt * 32 + r_local;
  #pragma unroll
  for (int q = 0; q < 4; ++q) xg[(size_t)m * 1024 + g[q]] = acc[q];
}

// ---------------------------------------------------------------------------
// Persistent cooperative LSTM: blocks [0,128) layer0 (step t),
// blocks [128,256) layer1 (step t-1). c-state in registers.
// h0buf/h1buf double buffered [2][B][H]: step s writes buf s&1, reads (s+1)&1.
// ---------------------------------------------------------------------------
__device__ __forceinline__ void stage_rows(const float* __restrict__ src,
                                           float4 (*lds)[32], int tid) {
  int r = tid & 31;
  const float* row = src + r * H_;
  #pragma unroll
  for (int j = 0; j < 8; ++j) {
    int c = (tid >> 5) + 8 * j;
    lds[c][r] = ld4(row + c * 4);
  }
}

__global__ __launch_bounds__(256) void lstm_persistent(
    const float* __restrict__ z, const float* __restrict__ W_lat,
    const float* __restrict__ b_lat,
    const float* __restrict__ xg,
    const float* __restrict__ W_hh0,
    const float* __restrict__ W_ih1, const float* __restrict__ W_hh1,
    const float* __restrict__ b_ih1, const float* __restrict__ b_hh1,
    float* __restrict__ h0buf, float* __restrict__ h1buf,
    __hip_bfloat16* __restrict__ hs) {
  cg::grid_group grid = cg::this_grid();
  __shared__ float4 ldsA[64][32];
  __shared__ float4 ldsB[64][32];

  int blk = blockIdx.x;
  bool isL0 = blk < 128;
  int blk_l = isL0 ? blk : blk - 128;
  int bt = blk_l & 3;        // 4 tiles of 32 b
  int ht = blk_l >> 2;       // 32 tiles of 8 h
  int tid = threadIdx.x;
  int b_local = tid & 31;
  int h_local = tid >> 5;
  int b = bt * 32 + b_local;
  int h = ht * 8 + h_local;
  int idx = b * H_ + h;

  // ---- h_init = z[b] . W_lat[h] + b_lat[h] ----
  {
    const float* zr = z + (size_t)b * L_;
    const float* wr = W_lat + (size_t)h * L_;
    float acc = b_lat[h];
    #pragma unroll 4
    for (int l = 0; l < L_; l += 4) acc += dot4(ld4(zr + l), ld4(wr + l));
    if (isL0) h0buf[BH_ + idx] = acc;
    else      h1buf[BH_ + idx] = acc;
  }
  float c_state = 0.f;
  grid.sync();

  const float* wi0 = W_hh0 + (size_t)h * H_;
  const float* wf0 = W_hh0 + (size_t)(H_ + h) * H_;
  const float* wg0 = W_hh0 + (size_t)(2 * H_ + h) * H_;
  const float* wo0 = W_hh0 + (size_t)(3 * H_ + h) * H_;
  const float* xi1 = W_ih1 + (size_t)h * H_;
  const float* xf1 = W_ih1 + (size_t)(H_ + h) * H_;
  const float* xg1 = W_ih1 + (size_t)(2 * H_ + h) * H_;
  const float* xo1 = W_ih1 + (size_t)(3 * H_ + h) * H_;
  const float* wi1 = W_hh1 + (size_t)h * H_;
  const float* wf1 = W_hh1 + (size_t)(H_ + h) * H_;
  const float* wg1 = W_hh1 + (size_t)(2 * H_ + h) * H_;
  const float* wo1 = W_hh1 + (size_t)(3 * H_ + h) * H_;
  float bias1_i = b_ih1[h] + b_hh1[h];
  float bias1_f = b_ih1[H_ + h] + b_hh1[H_ + h];
  float bias1_g = b_ih1[2 * H_ + h] + b_hh1[2 * H_ + h];
  float bias1_o = b_ih1[3 * H_ + h] + b_hh1[3 * H_ + h];

  for (int t = 0; t <= T_; ++t) {
    if (isL0) {
      if (t < T_) {
        stage_rows(h0buf + ((t + 1) & 1) * BH_ + bt * 32 * H_, ldsA, tid);
        int m = t * B_ + b;
        float ai = xg[(size_t)m * 1024 + h];
        float af = xg[(size_t)m * 1024 + 256 + h];
        float ag = xg[(size_t)m * 1024 + 512 + h];
        float ao = xg[(size_t)m * 1024 + 768 + h];
        __syncthreads();
        #pragma unroll 2
        for (int j = 0; j < 64; ++j) {
          float4 hv = ldsA[j][b_local];
          ai += dot4(hv, ld4(wi0 + j * 4));
          af += dot4(hv, ld4(wf0 + j * 4));
          ag += dot4(hv, ld4(wg0 + j * 4));
          ao += dot4(hv, ld4(wo0 + j * 4));
        }
        float ig = 1.f / (1.f + expf(-ai));
        float fg = 1.f / (1.f + expf(-af));
        float gg = tanhf(ag);
        float og = 1.f / (1.f + expf(-ao));
        c_state = fg * c_state + ig * gg;
        h0buf[(t & 1) * BH_ + idx] = og * tanhf(c_state);
      }
    } else {
      if (t >= 1) {
        int s = t - 1;
        stage_rows(h0buf + (s & 1) * BH_ + bt * 32 * H_, ldsA, tid);       // x = h0[s]
        stage_rows(h1buf + ((s + 1) & 1) * BH_ + bt * 32 * H_, ldsB, tid); // h1 prev
        __syncthreads();
        float ai = bias1_i, af = bias1_f, ag = bias1_g, ao = bias1_o;
        #pragma unroll 2
        for (int j = 0; j < 64; ++j) {
          float4 xv = ldsA[j][b_local];
          float4 hv = ldsB[j][b_local];
          ai += dot4(xv, ld4(xi1 + j * 4)) + dot4(hv, ld4(wi1 + j * 4));
          af += dot4(xv, ld4(xf1 + j * 4)) + dot4(hv, ld4(wf1 + j * 4));
          ag += dot4(xv, ld4(xg1 + j * 4)) + dot4(hv, ld4(wg1 + j * 4));
          ao += dot4(xv, ld4(xo1 + j * 4)) + dot4(hv, ld4(wo1 + j * 4));
        }
        float ig = 1.f / (1.f + expf(-ai));
        float fg = 1.f / (1.f + expf(-af));
        float gg = tanhf(ag);
        float og = 1.f / (1.f + expf(-ao));
        c_state = fg * c_state + ig * gg;
        float hn = og * tanhf(c_state);
        h1buf[(s & 1) * BH_ + idx] = hn;
        hs[(size_t)s * BH_ + idx] = __float2bfloat16(hn);
      }
    }
    grid.sync();
  }
}

// ---------------------------------------------------------------------------
// logits = hs @ WoutBf^T + b_out.  128x128 tile/block, 4 waves, 4x4 frags of
// 16x16x32, register double-buffered K loop (8 steps).
// ---------------------------------------------------------------------------
__global__ __launch_bounds__(256) void gemm_out(
    const __hip_bfloat16* __restrict__ hs,
    const __hip_bfloat16* __restrict__ Wb, const float* __restrict__ bout,
    float* __restrict__ out) {
  int lane = threadIdx.x & 63;
  int w = threadIdx.x >> 6;
  int wr = w >> 1, wc = w & 1;
  int m_base = blockIdx.x * 128 + wr * 64;
  int n_base = blockIdx.y * 128 + wc * 64;
  int row_in = lane & 15;
  int kgrp = lane >> 4;

  f32x4 acc[4][4];
  #pragma unroll
  for (int i = 0; i < 4; ++i)
    #pragma unroll
    for (int j = 0; j < 4; ++j) acc[i][j] = (f32x4){0.f, 0.f, 0.f, 0.f};

  bf16x8 a[2][4], bb[2][4];
  const bf16x8 bzero = {0, 0, 0, 0, 0, 0, 0, 0};

  #pragma unroll
  for (int mi = 0; mi < 4; ++mi)
    a[0][mi] = *(const bf16x8*)(hs + (size_t)(m_base + mi * 16 + row_in) * H_ + kgrp * 8);
  #pragma unroll
  for (int ni = 0; ni < 4; ++ni) {
    int v = n_base + ni * 16 + row_in;
    bb[0][ni] = (v < V_) ? *(const bf16x8*)(Wb + (size_t)v * H_ + kgrp * 8) : bzero;
  }

  #pragma unroll
  for (int kb = 0; kb < 8; ++kb) {
    int cur = kb & 1, nxt = cur ^ 1;
    if (kb < 7) {
      int k0 = (kb + 1) * 32 + kgrp * 8;
      #pragma unroll
      for (int mi = 0; mi < 4; ++mi)
        a[nxt][mi] = *(const bf16x8*)(hs + (size_t)(m_base + mi * 16 + row_in) * H_ + k0);
      #pragma unroll
      for (int ni = 0; ni < 4; ++ni) {
        int v = n_base + ni * 16 + row_in;
        bb[nxt][ni] = (v < V_) ? *(const bf16x8*)(Wb + (size_t)v * H_ + k0) : bzero;
      }
    }
    #pragma unroll
    for (int mi = 0; mi < 4; ++mi)
      #pragma unroll
      for (int ni = 0; ni < 4; ++ni)
        acc[mi][ni] = __builtin_amdgcn_mfma_f32_16x16x32_bf16(a[cur][mi], bb[cur][ni], acc[mi][ni], 0, 0, 0);
  }

  #pragma unroll
  for (int ni = 0; ni < 4; ++ni) {
    int v = n_base + ni * 16 + row_in;
    if (v >= V_) continue;
    float bias = bout[v];
    #pragma unroll
    for (int mi = 0; mi < 4; ++mi) {
      #pragma unroll
      for (int r = 0; r < 4; ++r) {
        int m = m_base + mi * 16 + kgrp * 4 + r;
        int tt = m >> 7;
        int bb_ = m & 127;
        out[((size_t)bb_ * T_ + tt) * V_ + v] = acc[mi][ni][r] + bias;
      }
    }
  }
}

// ---------------------------------------------------------------------------
extern "C" void kernel_launch(void* const* d_in, const int* in_sizes, int n_in,
                              void* d_out, int out_size, void* d_ws, size_t ws_size,
                              hipStream_t stream) {
  const float* z     = (const float*)d_in[0];
  const int*   targ  = (const int*)d_in[1];
  const float* emb   = (const float*)d_in[2];
  const float* W_ih0 = (const float*)d_in[3];
  const float* W_hh0 = (const float*)d_in[4];
  const float* b_ih0 = (const float*)d_in[5];
  const float* b_hh0 = (const float*)d_in[6];
  const float* W_ih1 = (const float*)d_in[7];
  const float* W_hh1 = (const float*)d_in[8];
  const float* b_ih1 = (const float*)d_in[9];
  const float* b_hh1 = (const float*)d_in[10];
  const float* W_out = (const float*)d_in[11];
  const float* b_out = (const float*)d_in[12];
  const float* W_lat = (const float*)d_in[13];
  const float* b_lat = (const float*)d_in[14];
  float* out = (float*)d_out;

  char* ws = (char*)d_ws;
  float* h0buf = (float*)(ws);                              // 2*B*H f32 = 256 KB
  float* h1buf = (float*)(ws + 262144);                     // 256 KB
  __hip_bfloat16* hs = (__hip_bfloat16*)(ws + 524288);      // 4 MB
  float* xg = (float*)(ws + 4718592);                       // 33.5 MB
  __hip_bfloat16* WoutBf = (__hip_bfloat16*)(ws + 38273024); // 15.6 MB

  conv_wout<<<3816, 256, 0, stream>>>(W_out, WoutBf, V_ * H_);
  {
    dim3 g(256, 32);
    xg_kernel<<<g, 256, 0, stream>>>(targ, emb, W_ih0, b_ih0, b_hh0, xg);
  }
  {
    void* args[] = {(void*)&z, (void*)&W_lat, (void*)&b_lat, (void*)&xg,
                    (void*)&W_hh0,
                    (void*)&W_ih1, (void*)&W_hh1, (void*)&b_ih1, (void*)&b_hh1,
                    (void*)&h0buf, (void*)&h1buf, (void*)&hs};
    hipLaunchCooperativeKernel((void*)lstm_persistent, dim3(256), dim3(256),
                               args, 0, stream);
  }
  {
    dim3 g(64, 239);
    gemm_out<<<g, 256, 0, stream>>>(hs, WoutBf, b_out, out);
  }
}

// Round 6
// 1719.528 us; speedup vs baseline: 2.5265x; 2.5265x over previous
//
#include <hip/hip_runtime.h>
#include <hip/hip_bf16.h>

#define B_ 128
#define T_ 64
#define H_ 256
#define E_ 256
#define L_ 512
#define V_ 30522
#define EOS_ 2
#define BH_ (B_ * H_)

typedef __attribute__((ext_vector_type(8))) short bf16x8;
typedef __attribute__((ext_vector_type(4))) float f32x4;

__device__ __forceinline__ float4 ld4(const float* p) { return *(const float4*)p; }
__device__ __forceinline__ float dot4(float4 a, float4 b) {
  return a.x * b.x + a.y * b.y + a.z * b.z + a.w * b.w;
}
__device__ __forceinline__ float sigf(float x) {
  return __builtin_amdgcn_rcpf(1.f + __expf(-x));
}
__device__ __forceinline__ float tanh_fast(float x) {
  float e = __expf(2.f * x);
  return 1.f - 2.f * __builtin_amdgcn_rcpf(e + 1.f);
}
__device__ __forceinline__ f32x4 mfma16(bf16x8 a, bf16x8 b, f32x4 c) {
  return __builtin_amdgcn_mfma_f32_16x16x32_bf16(a, b, c, 0, 0, 0);
}

// ---------------------------------------------------------------------------
// generic f32 -> bf16 convert (total % 8 == 0)
// ---------------------------------------------------------------------------
__global__ __launch_bounds__(256) void conv_bf16(
    const float* __restrict__ src, __hip_bfloat16* __restrict__ dst, int total) {
  int i = (blockIdx.x * 256 + threadIdx.x) * 8;
  if (i + 8 <= total) {
    float4 lo = ld4(src + i), hi = ld4(src + i + 4);
    union { bf16x8 v8; __hip_bfloat16 e[8]; } u;
    u.e[0] = __float2bfloat16(lo.x); u.e[1] = __float2bfloat16(lo.y);
    u.e[2] = __float2bfloat16(lo.z); u.e[3] = __float2bfloat16(lo.w);
    u.e[4] = __float2bfloat16(hi.x); u.e[5] = __float2bfloat16(hi.y);
    u.e[6] = __float2bfloat16(hi.z); u.e[7] = __float2bfloat16(hi.w);
    *(bf16x8*)(dst + i) = u.v8;
  }
}

// ---------------------------------------------------------------------------
// init: h_init = z @ W_lat^T + b_lat -> slot 0 of h0 & hs (hi+res); c = 0
// ---------------------------------------------------------------------------
__global__ __launch_bounds__(256) void init_kernel(
    const float* __restrict__ z, const float* __restrict__ W_lat,
    const float* __restrict__ b_lat,
    __hip_bfloat16* __restrict__ h0hi, __hip_bfloat16* __restrict__ h0res,
    __hip_bfloat16* __restrict__ hshi, __hip_bfloat16* __restrict__ hsres,
    float* __restrict__ cstate) {
  int b = blockIdx.x;
  int h = threadIdx.x;
  const float* zr = z + (size_t)b * L_;
  const float* wr = W_lat + (size_t)h * L_;
  float acc = b_lat[h];
  #pragma unroll 4
  for (int l = 0; l < L_; l += 4) acc += dot4(ld4(zr + l), ld4(wr + l));
  __hip_bfloat16 hi = __float2bfloat16(acc);
  __hip_bfloat16 re = __float2bfloat16(acc - __bfloat162float(hi));
  int idx = b * H_ + h;
  h0hi[idx] = hi; h0res[idx] = re;
  hshi[idx] = hi; hsres[idx] = re;
  cstate[idx] = 0.f;
  cstate[BH_ + idx] = 0.f;
}

// ---------------------------------------------------------------------------
// One lagged LSTM step, regular launch. 32 blocks x 256 threads:
//   blocks [0,16): layer0 step t (t < T)
//   blocks [16,32): layer1 step s = t-1 (t >= 1)
// All cross-half data deps are produced by PREVIOUS launches (stream-ordered):
//   L0@t reads h0 slot t (written @t-1); L1@t reads h0 slot t (written @t-1)
//   and hs slot t-1 (written @t-1). c-state in cstate[layer][B][H] f32.
// Histories hi/res split: h = hi + res (two bf16), consumed as 2 MFMA chains.
// ---------------------------------------------------------------------------
__global__ __launch_bounds__(256, 1) void lstm_step_mfma(
    int t,
    const int* __restrict__ targ, const __hip_bfloat16* __restrict__ embB,
    const __hip_bfloat16* __restrict__ Wih0B, const __hip_bfloat16* __restrict__ Whh0B,
    const float* __restrict__ b_ih0, const float* __restrict__ b_hh0,
    const __hip_bfloat16* __restrict__ Wih1B, const __hip_bfloat16* __restrict__ Whh1B,
    const float* __restrict__ b_ih1, const float* __restrict__ b_hh1,
    __hip_bfloat16* __restrict__ h0hi, __hip_bfloat16* __restrict__ h0res,
    __hip_bfloat16* __restrict__ hshi, __hip_bfloat16* __restrict__ hsres,
    float* __restrict__ cstate) {
  const int blk = blockIdx.x;
  const bool isL0 = blk < 16;
  if (isL0) { if (t >= T_) return; }
  else      { if (t < 1)  return; }

  const int chunk = isL0 ? blk : blk - 16;
  const int tid = threadIdx.x;
  const int lane = tid & 63;
  const int wave = tid >> 6;
  const int col = lane & 15;
  const int klo = lane >> 4;
  const int mbase = wave * 32;
  const int hcol = chunk * 16 + col;

  const float* bi = isL0 ? b_ih0 : b_ih1;
  const float* bh = isL0 ? b_hh0 : b_hh1;
  float bias[4];
  #pragma unroll
  for (int g = 0; g < 4; ++g) bias[g] = bi[g * 256 + hcol] + bh[g * 256 + hcol];

  const __hip_bfloat16* W1 = isL0 ? Wih0B : Wih1B;
  const __hip_bfloat16* W2 = isL0 ? Whh0B : Whh1B;

  // c-state: lane element r of acc row-group -> row mbase + mt*16 + klo*4 + r
  float* cs = cstate + (isL0 ? 0 : BH_);
  f32x4 cst[2];
  #pragma unroll
  for (int mt = 0; mt < 2; ++mt)
    #pragma unroll
    for (int r = 0; r < 4; ++r)
      cst[mt][r] = cs[(size_t)(mbase + mt * 16 + klo * 4 + r) * H_ + hcol];

  const int b0 = mbase + col;
  const int b1 = mbase + 16 + col;

  f32x4 acc[2][4];
  #pragma unroll
  for (int mt = 0; mt < 2; ++mt)
    #pragma unroll
    for (int g = 0; g < 4; ++g) acc[mt][g] = (f32x4){0.f, 0.f, 0.f, 0.f};

  const int s = t - 1;  // layer1 step
  // x-path operand rows
  const __hip_bfloat16 *x0, *x1, *xr0 = nullptr, *xr1 = nullptr;
  if (isL0) {
    int tok0 = (t == 0) ? EOS_ : targ[b0 * T_ + t - 1];
    int tok1 = (t == 0) ? EOS_ : targ[b1 * T_ + t - 1];
    x0 = embB + (size_t)tok0 * E_;
    x1 = embB + (size_t)tok1 * E_;
  } else {
    x0 = h0hi + (size_t)t * BH_ + b0 * H_;
    x1 = h0hi + (size_t)t * BH_ + b1 * H_;
    xr0 = h0res + (size_t)t * BH_ + b0 * H_;
    xr1 = h0res + (size_t)t * BH_ + b1 * H_;
  }
  // recurrent-path operand rows (hi + res)
  const __hip_bfloat16* Hhi = isL0 ? h0hi : hshi;
  const __hip_bfloat16* Hre = isL0 ? h0res : hsres;
  size_t hoff = (size_t)(isL0 ? t : s) * BH_;
  const __hip_bfloat16* hh0 = Hhi + hoff + b0 * H_;
  const __hip_bfloat16* hh1 = Hhi + hoff + b1 * H_;
  const __hip_bfloat16* hr0 = Hre + hoff + b0 * H_;
  const __hip_bfloat16* hr1 = Hre + hoff + b1 * H_;

  #pragma unroll
  for (int ks = 0; ks < 8; ++ks) {
    const int ko = ks * 32 + klo * 8;
    // B-frags for this k-slice (loaded fresh each step; L1/L2-hot)
    bf16x8 w1[4], w2[4];
    #pragma unroll
    for (int g = 0; g < 4; ++g) {
      int row = g * 256 + hcol;
      w1[g] = *(const bf16x8*)(W1 + (size_t)row * 256 + ko);
      w2[g] = *(const bf16x8*)(W2 + (size_t)row * 256 + ko);
    }
    bf16x8 ax0 = *(const bf16x8*)(x0 + ko);
    bf16x8 ax1 = *(const bf16x8*)(x1 + ko);
    bf16x8 ahh0 = *(const bf16x8*)(hh0 + ko);
    bf16x8 ahh1 = *(const bf16x8*)(hh1 + ko);
    bf16x8 ahr0 = *(const bf16x8*)(hr0 + ko);
    bf16x8 ahr1 = *(const bf16x8*)(hr1 + ko);
    #pragma unroll
    for (int g = 0; g < 4; ++g) {
      acc[0][g] = mfma16(ax0, w1[g], acc[0][g]);
      acc[1][g] = mfma16(ax1, w1[g], acc[1][g]);
      acc[0][g] = mfma16(ahh0, w2[g], acc[0][g]);
      acc[1][g] = mfma16(ahh1, w2[g], acc[1][g]);
      acc[0][g] = mfma16(ahr0, w2[g], acc[0][g]);
      acc[1][g] = mfma16(ahr1, w2[g], acc[1][g]);
    }
    if (!isL0) {
      bf16x8 axr0 = *(const bf16x8*)(xr0 + ko);
      bf16x8 axr1 = *(const bf16x8*)(xr1 + ko);
      #pragma unroll
      for (int g = 0; g < 4; ++g) {
        acc[0][g] = mfma16(axr0, w1[g], acc[0][g]);
        acc[1][g] = mfma16(axr1, w1[g], acc[1][g]);
      }
    }
  }

  // epilogue: gates -> h, write hi/res, persist c
  __hip_bfloat16* whi = (isL0 ? h0hi : hshi) + (size_t)((isL0 ? t : s) + 1) * BH_;
  __hip_bfloat16* wre = (isL0 ? h0res : hsres) + (size_t)((isL0 ? t : s) + 1) * BH_;
  #pragma unroll
  for (int mt = 0; mt < 2; ++mt) {
    #pragma unroll
    for (int r = 0; r < 4; ++r) {
      float iv = sigf(acc[mt][0][r] + bias[0]);
      float fv = sigf(acc[mt][1][r] + bias[1]);
      float gv = tanh_fast(acc[mt][2][r] + bias[2]);
      float ov = sigf(acc[mt][3][r] + bias[3]);
      float c = fv * cst[mt][r] + iv * gv;
      cst[mt][r] = c;
      float h = ov * tanh_fast(c);
      __hip_bfloat16 hi = __float2bfloat16(h);
      __hip_bfloat16 re = __float2bfloat16(h - __bfloat162float(hi));
      int brow = mbase + mt * 16 + klo * 4 + r;
      whi[(size_t)brow * H_ + hcol] = hi;
      wre[(size_t)brow * H_ + hcol] = re;
    }
  }
  #pragma unroll
  for (int mt = 0; mt < 2; ++mt)
    #pragma unroll
    for (int r = 0; r < 4; ++r)
      cs[(size_t)(mbase + mt * 16 + klo * 4 + r) * H_ + hcol] = cst[mt][r];
}

// ---------------------------------------------------------------------------
// logits = hs @ WoutBf^T + b_out.  128x128 tile, BK=32, double-buffered
// global_load_lds staging, LDS frag reads. Output [B][T][V] f32.
// ---------------------------------------------------------------------------
__global__ __launch_bounds__(256) void gemm_out(
    const __hip_bfloat16* __restrict__ hs,
    const __hip_bfloat16* __restrict__ Wb, const float* __restrict__ bout,
    float* __restrict__ out) {
  __shared__ __hip_bfloat16 ldsA[2][128 * 32];
  __shared__ __hip_bfloat16 ldsB[2][128 * 32];

  const int tid = threadIdx.x;
  const int lane = tid & 63;
  const int wave = tid >> 6;
  const int wr = wave >> 1, wc = wave & 1;
  const int m0 = blockIdx.x * 128;
  const int n0 = blockIdx.y * 128;
  const int row_in = lane & 15;
  const int kgrp = lane >> 4;

  auto stage = [&](int kb, int buf) {
    #pragma unroll
    for (int p = 0; p < 2; ++p) {
      int slot = p * 256 + wave * 64 + lane;
      int row = slot >> 2;
      int k16 = slot & 3;
      const __hip_bfloat16* srcA = hs + (size_t)(m0 + row) * H_ + kb * 32 + k16 * 8;
      int rn = n0 + row; if (rn >= V_) rn = V_ - 1;
      const __hip_bfloat16* srcB = Wb + (size_t)rn * H_ + kb * 32 + k16 * 8;
      __hip_bfloat16* dstA = &ldsA[buf][0] + (p * 2048 + wave * 512);
      __hip_bfloat16* dstB = &ldsB[buf][0] + (p * 2048 + wave * 512);
      __builtin_amdgcn_global_load_lds(
          (const __attribute__((address_space(1))) unsigned int*)srcA,
          (__attribute__((address_space(3))) unsigned int*)dstA, 16, 0, 0);
      __builtin_amdgcn_global_load_lds(
          (const __attribute__((address_space(1))) unsigned int*)srcB,
          (__attribute__((address_space(3))) unsigned int*)dstB, 16, 0, 0);
    }
  };

  f32x4 acc[4][4];
  #pragma unroll
  for (int i = 0; i < 4; ++i)
    #pragma unroll
    for (int j = 0; j < 4; ++j) acc[i][j] = (f32x4){0.f, 0.f, 0.f, 0.f};

  stage(0, 0);
  __syncthreads();

  int buf = 0;
  for (int kb = 0; kb < 8; ++kb) {
    if (kb < 7) stage(kb + 1, buf ^ 1);
    bf16x8 a[4], b[4];
    #pragma unroll
    for (int mi = 0; mi < 4; ++mi) {
      int row = wr * 64 + mi * 16 + row_in;
      a[mi] = *(const bf16x8*)(&ldsA[buf][0] + row * 32 + kgrp * 8);
    }
    #pragma unroll
    for (int ni = 0; ni < 4; ++ni) {
      int row = wc * 64 + ni * 16 + row_in;
      b[ni] = *(const bf16x8*)(&ldsB[buf][0] + row * 32 + kgrp * 8);
    }
    #pragma unroll
    for (int mi = 0; mi < 4; ++mi)
      #pragma unroll
      for (int ni = 0; ni < 4; ++ni)
        acc[mi][ni] = mfma16(a[mi], b[ni], acc[mi][ni]);
    __syncthreads();
    buf ^= 1;
  }

  #pragma unroll
  for (int ni = 0; ni < 4; ++ni) {
    int v = n0 + wc * 64 + ni * 16 + row_in;
    if (v >= V_) continue;
    float bias = bout[v];
    #pragma unroll
    for (int mi = 0; mi < 4; ++mi) {
      #pragma unroll
      for (int r = 0; r < 4; ++r) {
        int m = m0 + wr * 64 + mi * 16 + kgrp * 4 + r;
        int tt = m >> 7;
        int bb_ = m & 127;
        out[((size_t)bb_ * T_ + tt) * V_ + v] = acc[mi][ni][r] + bias;
      }
    }
  }
}

// ---------------------------------------------------------------------------
extern "C" void kernel_launch(void* const* d_in, const int* in_sizes, int n_in,
                              void* d_out, int out_size, void* d_ws, size_t ws_size,
                              hipStream_t stream) {
  const float* z     = (const float*)d_in[0];
  const int*   targ  = (const int*)d_in[1];
  const float* emb   = (const float*)d_in[2];
  const float* W_ih0 = (const float*)d_in[3];
  const float* W_hh0 = (const float*)d_in[4];
  const float* b_ih0 = (const float*)d_in[5];
  const float* b_hh0 = (const float*)d_in[6];
  const float* W_ih1 = (const float*)d_in[7];
  const float* W_hh1 = (const float*)d_in[8];
  const float* b_ih1 = (const float*)d_in[9];
  const float* b_hh1 = (const float*)d_in[10];
  const float* W_out = (const float*)d_in[11];
  const float* b_out = (const float*)d_in[12];
  const float* W_lat = (const float*)d_in[13];
  const float* b_lat = (const float*)d_in[14];
  float* out = (float*)d_out;

  char* ws = (char*)d_ws;
  __hip_bfloat16* h0hi  = (__hip_bfloat16*)(ws);              // 65*BH*2 = 4,259,840
  __hip_bfloat16* h0res = (__hip_bfloat16*)(ws + 4259840);
  __hip_bfloat16* hshi  = (__hip_bfloat16*)(ws + 8519680);
  __hip_bfloat16* hsres = (__hip_bfloat16*)(ws + 12779520);
  __hip_bfloat16* embB  = (__hip_bfloat16*)(ws + 17039360);   // 15,627,264
  __hip_bfloat16* Wih0B = (__hip_bfloat16*)(ws + 32666624);   // 524,288
  __hip_bfloat16* Whh0B = (__hip_bfloat16*)(ws + 33190912);
  __hip_bfloat16* Wih1B = (__hip_bfloat16*)(ws + 33715200);
  __hip_bfloat16* Whh1B = (__hip_bfloat16*)(ws + 34239488);
  __hip_bfloat16* WoutB = (__hip_bfloat16*)(ws + 34763776);   // 15,627,264
  float* cstate = (float*)(ws + 50391040);                    // 2*BH*4 = 262,144

  conv_bf16<<<3816, 256, 0, stream>>>(emb, embB, V_ * E_);
  conv_bf16<<<128, 256, 0, stream>>>(W_ih0, Wih0B, 1024 * 256);
  conv_bf16<<<128, 256, 0, stream>>>(W_hh0, Whh0B, 1024 * 256);
  conv_bf16<<<128, 256, 0, stream>>>(W_ih1, Wih1B, 1024 * 256);
  conv_bf16<<<128, 256, 0, stream>>>(W_hh1, Whh1B, 1024 * 256);
  conv_bf16<<<3816, 256, 0, stream>>>(W_out, WoutB, V_ * H_);
  init_kernel<<<128, 256, 0, stream>>>(z, W_lat, b_lat, h0hi, h0res, hshi, hsres, cstate);

  for (int t = 0; t <= T_; ++t) {
    lstm_step_mfma<<<32, 256, 0, stream>>>(
        t, targ, embB,
        Wih0B, Whh0B, b_ih0, b_hh0,
        Wih1B, Whh1B, b_ih1, b_hh1,
        h0hi, h0res, hshi, hsres, cstate);
  }

  {
    dim3 g(64, 239);
    gemm_out<<<g, 256, 0, stream>>>(hshi + BH_, WoutB, b_out, out);
  }
}

// Round 7
// 1541.584 us; speedup vs baseline: 2.8181x; 1.1154x over previous
//
#include <hip/hip_runtime.h>
#include <hip/hip_bf16.h>

#define B_ 128
#define T_ 64
#define H_ 256
#define E_ 256
#define L_ 512
#define V_ 30522
#define EOS_ 2
#define BH_ (B_ * H_)

typedef __attribute__((ext_vector_type(8))) short bf16x8;
typedef __attribute__((ext_vector_type(4))) float f32x4;

__device__ __forceinline__ float4 ld4(const float* p) { return *(const float4*)p; }
__device__ __forceinline__ float dot4(float4 a, float4 b) {
  return a.x * b.x + a.y * b.y + a.z * b.z + a.w * b.w;
}
__device__ __forceinline__ float sigf(float x) {
  return __builtin_amdgcn_rcpf(1.f + __expf(-x));
}
__device__ __forceinline__ float tanh_fast(float x) {
  float e = __expf(2.f * x);
  return 1.f - 2.f * __builtin_amdgcn_rcpf(e + 1.f);
}
__device__ __forceinline__ f32x4 mfma16(bf16x8 a, bf16x8 b, f32x4 c) {
  return __builtin_amdgcn_mfma_f32_16x16x32_bf16(a, b, c, 0, 0, 0);
}

// ---------------------------------------------------------------------------
// generic f32 -> bf16 convert (total % 8 == 0)
// ---------------------------------------------------------------------------
__global__ __launch_bounds__(256) void conv_bf16(
    const float* __restrict__ src, __hip_bfloat16* __restrict__ dst, int total) {
  int i = (blockIdx.x * 256 + threadIdx.x) * 8;
  if (i + 8 <= total) {
    float4 lo = ld4(src + i), hi = ld4(src + i + 4);
    union { bf16x8 v8; __hip_bfloat16 e[8]; } u;
    u.e[0] = __float2bfloat16(lo.x); u.e[1] = __float2bfloat16(lo.y);
    u.e[2] = __float2bfloat16(lo.z); u.e[3] = __float2bfloat16(lo.w);
    u.e[4] = __float2bfloat16(hi.x); u.e[5] = __float2bfloat16(hi.y);
    u.e[6] = __float2bfloat16(hi.z); u.e[7] = __float2bfloat16(hi.w);
    *(bf16x8*)(dst + i) = u.v8;
  }
}

__global__ void reset_cnt(int* __restrict__ c) { c[threadIdx.x] = 0; }

// ---------------------------------------------------------------------------
// init: h_init = z @ W_lat^T + b_lat -> slot 0 of h0 & hs (hi+res)
// ---------------------------------------------------------------------------
__global__ __launch_bounds__(256) void init_kernel(
    const float* __restrict__ z, const float* __restrict__ W_lat,
    const float* __restrict__ b_lat,
    __hip_bfloat16* __restrict__ h0hi, __hip_bfloat16* __restrict__ h0res,
    __hip_bfloat16* __restrict__ hshi, __hip_bfloat16* __restrict__ hsres) {
  int b = blockIdx.x;
  int h = threadIdx.x;
  const float* zr = z + (size_t)b * L_;
  const float* wr = W_lat + (size_t)h * L_;
  float acc = b_lat[h];
  #pragma unroll 4
  for (int l = 0; l < L_; l += 4) acc += dot4(ld4(zr + l), ld4(wr + l));
  __hip_bfloat16 hi = __float2bfloat16(acc);
  __hip_bfloat16 re = __float2bfloat16(acc - __bfloat162float(hi));
  int idx = b * H_ + h;
  h0hi[idx] = hi; h0res[idx] = re;
  hshi[idx] = hi; hsres[idx] = re;
}

// ---------------------------------------------------------------------------
// Persistent MFMA recurrence, REGULAR launch (32 blocks, all co-resident on
// a 256-CU chip), flag-based sync. The release/acquire + fence primitive
// sequence is the same one cg::grid.sync uses (HW-validated in R2); only the
// cooperative LAUNCHER was broken (R3/R4).
//   blocks [0,16): layer0; blocks [16,32): layer1. Weights stay in VGPRs.
//   cnt0[t]==16 <=> h0 slot t+1 complete; cnt1[t]==16 <=> hs slot t+1 done.
// Spin caps (~1e5 iters) turn a protocol bug into a wrong answer, not a hang.
// ---------------------------------------------------------------------------
__device__ __forceinline__ void wait_cnt(int* p) {
  if (threadIdx.x == 0) {
    int it = 0;
    while (__hip_atomic_load(p, __ATOMIC_ACQUIRE, __HIP_MEMORY_SCOPE_AGENT) < 16 &&
           it < (1 << 19)) {
      __builtin_amdgcn_s_sleep(2);
      ++it;
    }
  }
  __syncthreads();
}

__device__ __forceinline__ void signal_cnt(int* p) {
  __syncthreads();               // all waves' stores drained (waitcnt before barrier)
  __threadfence();               // agent-scope: writeback to coherence point
  if (threadIdx.x == 0)
    __hip_atomic_fetch_add(p, 1, __ATOMIC_RELEASE, __HIP_MEMORY_SCOPE_AGENT);
}

__global__ __launch_bounds__(256, 1) void lstm_persist(
    const int* __restrict__ targ, const __hip_bfloat16* __restrict__ embB,
    const __hip_bfloat16* __restrict__ Wih0B, const __hip_bfloat16* __restrict__ Whh0B,
    const float* __restrict__ b_ih0, const float* __restrict__ b_hh0,
    const __hip_bfloat16* __restrict__ Wih1B, const __hip_bfloat16* __restrict__ Whh1B,
    const float* __restrict__ b_ih1, const float* __restrict__ b_hh1,
    __hip_bfloat16* __restrict__ h0hi, __hip_bfloat16* __restrict__ h0res,
    __hip_bfloat16* __restrict__ hshi, __hip_bfloat16* __restrict__ hsres,
    int* __restrict__ cnt0, int* __restrict__ cnt1) {
  const int blk = blockIdx.x;
  const bool isL0 = blk < 16;
  const int chunk = isL0 ? blk : blk - 16;
  const int tid = threadIdx.x;
  const int lane = tid & 63;
  const int wave = tid >> 6;
  const int col = lane & 15;
  const int klo = lane >> 4;
  const int mbase = wave * 32;
  const int hcol = chunk * 16 + col;

  const float* bi = isL0 ? b_ih0 : b_ih1;
  const float* bh = isL0 ? b_hh0 : b_hh1;
  float bias[4];
  #pragma unroll
  for (int g = 0; g < 4; ++g) bias[g] = bi[g * 256 + hcol] + bh[g * 256 + hcol];

  // weight-stationary: B-frags for the whole run (~256 VGPR)
  const __hip_bfloat16* W1 = isL0 ? Wih0B : Wih1B;
  const __hip_bfloat16* W2 = isL0 ? Whh0B : Whh1B;
  bf16x8 bw1[4][8], bw2[4][8];
  #pragma unroll
  for (int g = 0; g < 4; ++g) {
    int row = g * 256 + hcol;
    #pragma unroll
    for (int ks = 0; ks < 8; ++ks) {
      bw1[g][ks] = *(const bf16x8*)(W1 + (size_t)row * 256 + ks * 32 + klo * 8);
      bw2[g][ks] = *(const bf16x8*)(W2 + (size_t)row * 256 + ks * 32 + klo * 8);
    }
  }

  const int b0 = mbase + col;
  const int b1 = mbase + 16 + col;
  f32x4 cst[2];
  cst[0] = (f32x4){0.f, 0.f, 0.f, 0.f};
  cst[1] = (f32x4){0.f, 0.f, 0.f, 0.f};

  for (int t = 0; t < T_; ++t) {
    if (isL0) {
      if (t) wait_cnt(cnt0 + t - 1);            // h0 slot t complete
    } else {
      wait_cnt(cnt0 + t);                       // h0 slot t+1 complete
      if (t) wait_cnt(cnt1 + t - 1);            // hs slot t complete
    }

    f32x4 acc[2][4];
    #pragma unroll
    for (int mt = 0; mt < 2; ++mt)
      #pragma unroll
      for (int g = 0; g < 4; ++g) acc[mt][g] = (f32x4){0.f, 0.f, 0.f, 0.f};

    if (isL0) {
      int tok0 = (t == 0) ? EOS_ : targ[b0 * T_ + t - 1];
      int tok1 = (t == 0) ? EOS_ : targ[b1 * T_ + t - 1];
      const __hip_bfloat16* x0 = embB + (size_t)tok0 * E_;
      const __hip_bfloat16* x1 = embB + (size_t)tok1 * E_;
      const __hip_bfloat16* hh0 = h0hi + (size_t)t * BH_ + b0 * H_;
      const __hip_bfloat16* hh1 = h0hi + (size_t)t * BH_ + b1 * H_;
      const __hip_bfloat16* hr0 = h0res + (size_t)t * BH_ + b0 * H_;
      const __hip_bfloat16* hr1 = h0res + (size_t)t * BH_ + b1 * H_;
      #pragma unroll
      for (int ks = 0; ks < 8; ++ks) {
        const int ko = ks * 32 + klo * 8;
        bf16x8 ax0 = *(const bf16x8*)(x0 + ko);
        bf16x8 ax1 = *(const bf16x8*)(x1 + ko);
        bf16x8 ahh0 = *(const bf16x8*)(hh0 + ko);
        bf16x8 ahh1 = *(const bf16x8*)(hh1 + ko);
        bf16x8 ahr0 = *(const bf16x8*)(hr0 + ko);
        bf16x8 ahr1 = *(const bf16x8*)(hr1 + ko);
        #pragma unroll
        for (int g = 0; g < 4; ++g) {
          acc[0][g] = mfma16(ax0, bw1[g][ks], acc[0][g]);
          acc[1][g] = mfma16(ax1, bw1[g][ks], acc[1][g]);
          acc[0][g] = mfma16(ahh0, bw2[g][ks], acc[0][g]);
          acc[1][g] = mfma16(ahh1, bw2[g][ks], acc[1][g]);
          acc[0][g] = mfma16(ahr0, bw2[g][ks], acc[0][g]);
          acc[1][g] = mfma16(ahr1, bw2[g][ks], acc[1][g]);
        }
      }
    } else {
      const __hip_bfloat16* xh0 = h0hi + (size_t)(t + 1) * BH_ + b0 * H_;
      const __hip_bfloat16* xh1 = h0hi + (size_t)(t + 1) * BH_ + b1 * H_;
      const __hip_bfloat16* xr0 = h0res + (size_t)(t + 1) * BH_ + b0 * H_;
      const __hip_bfloat16* xr1 = h0res + (size_t)(t + 1) * BH_ + b1 * H_;
      const __hip_bfloat16* hh0 = hshi + (size_t)t * BH_ + b0 * H_;
      const __hip_bfloat16* hh1 = hshi + (size_t)t * BH_ + b1 * H_;
      const __hip_bfloat16* hr0 = hsres + (size_t)t * BH_ + b0 * H_;
      const __hip_bfloat16* hr1 = hsres + (size_t)t * BH_ + b1 * H_;
      #pragma unroll
      for (int ks = 0; ks < 8; ++ks) {
        const int ko = ks * 32 + klo * 8;
        bf16x8 axh0 = *(const bf16x8*)(xh0 + ko);
        bf16x8 axh1 = *(const bf16x8*)(xh1 + ko);
        bf16x8 axr0 = *(const bf16x8*)(xr0 + ko);
        bf16x8 axr1 = *(const bf16x8*)(xr1 + ko);
        bf16x8 ahh0 = *(const bf16x8*)(hh0 + ko);
        bf16x8 ahh1 = *(const bf16x8*)(hh1 + ko);
        bf16x8 ahr0 = *(const bf16x8*)(hr0 + ko);
        bf16x8 ahr1 = *(const bf16x8*)(hr1 + ko);
        #pragma unroll
        for (int g = 0; g < 4; ++g) {
          acc[0][g] = mfma16(axh0, bw1[g][ks], acc[0][g]);
          acc[1][g] = mfma16(axh1, bw1[g][ks], acc[1][g]);
          acc[0][g] = mfma16(axr0, bw1[g][ks], acc[0][g]);
          acc[1][g] = mfma16(axr1, bw1[g][ks], acc[1][g]);
          acc[0][g] = mfma16(ahh0, bw2[g][ks], acc[0][g]);
          acc[1][g] = mfma16(ahh1, bw2[g][ks], acc[1][g]);
          acc[0][g] = mfma16(ahr0, bw2[g][ks], acc[0][g]);
          acc[1][g] = mfma16(ahr1, bw2[g][ks], acc[1][g]);
        }
      }
    }

    // epilogue: gates -> h, write slot t+1 (hi/res), c stays in regs
    __hip_bfloat16* whi = (isL0 ? h0hi : hshi) + (size_t)(t + 1) * BH_;
    __hip_bfloat16* wre = (isL0 ? h0res : hsres) + (size_t)(t + 1) * BH_;
    #pragma unroll
    for (int mt = 0; mt < 2; ++mt) {
      #pragma unroll
      for (int r = 0; r < 4; ++r) {
        float iv = sigf(acc[mt][0][r] + bias[0]);
        float fv = sigf(acc[mt][1][r] + bias[1]);
        float gv = tanh_fast(acc[mt][2][r] + bias[2]);
        float ov = sigf(acc[mt][3][r] + bias[3]);
        float c = fv * cst[mt][r] + iv * gv;
        cst[mt][r] = c;
        float h = ov * tanh_fast(c);
        __hip_bfloat16 hi = __float2bfloat16(h);
        __hip_bfloat16 re = __float2bfloat16(h - __bfloat162float(hi));
        int brow = mbase + mt * 16 + klo * 4 + r;
        whi[(size_t)brow * H_ + hcol] = hi;
        wre[(size_t)brow * H_ + hcol] = re;
      }
    }
    signal_cnt((isL0 ? cnt0 : cnt1) + t);
  }
}

// ---------------------------------------------------------------------------
// logits = hs @ WoutBf^T + b_out.  128x128 tile, BK=32, double-buffered
// global_load_lds staging, LDS frag reads. Output [B][T][V] f32. (unchanged)
// ---------------------------------------------------------------------------
__global__ __launch_bounds__(256) void gemm_out(
    const __hip_bfloat16* __restrict__ hs,
    const __hip_bfloat16* __restrict__ Wb, const float* __restrict__ bout,
    float* __restrict__ out) {
  __shared__ __hip_bfloat16 ldsA[2][128 * 32];
  __shared__ __hip_bfloat16 ldsB[2][128 * 32];

  const int tid = threadIdx.x;
  const int lane = tid & 63;
  const int wave = tid >> 6;
  const int wr = wave >> 1, wc = wave & 1;
  const int m0 = blockIdx.x * 128;
  const int n0 = blockIdx.y * 128;
  const int row_in = lane & 15;
  const int kgrp = lane >> 4;

  auto stage = [&](int kb, int buf) {
    #pragma unroll
    for (int p = 0; p < 2; ++p) {
      int slot = p * 256 + wave * 64 + lane;
      int row = slot >> 2;
      int k16 = slot & 3;
      const __hip_bfloat16* srcA = hs + (size_t)(m0 + row) * H_ + kb * 32 + k16 * 8;
      int rn = n0 + row; if (rn >= V_) rn = V_ - 1;
      const __hip_bfloat16* srcB = Wb + (size_t)rn * H_ + kb * 32 + k16 * 8;
      __hip_bfloat16* dstA = &ldsA[buf][0] + (p * 2048 + wave * 512);
      __hip_bfloat16* dstB = &ldsB[buf][0] + (p * 2048 + wave * 512);
      __builtin_amdgcn_global_load_lds(
          (const __attribute__((address_space(1))) unsigned int*)srcA,
          (__attribute__((address_space(3))) unsigned int*)dstA, 16, 0, 0);
      __builtin_amdgcn_global_load_lds(
          (const __attribute__((address_space(1))) unsigned int*)srcB,
          (__attribute__((address_space(3))) unsigned int*)dstB, 16, 0, 0);
    }
  };

  f32x4 acc[4][4];
  #pragma unroll
  for (int i = 0; i < 4; ++i)
    #pragma unroll
    for (int j = 0; j < 4; ++j) acc[i][j] = (f32x4){0.f, 0.f, 0.f, 0.f};

  stage(0, 0);
  __syncthreads();

  int buf = 0;
  for (int kb = 0; kb < 8; ++kb) {
    if (kb < 7) stage(kb + 1, buf ^ 1);
    bf16x8 a[4], b[4];
    #pragma unroll
    for (int mi = 0; mi < 4; ++mi) {
      int row = wr * 64 + mi * 16 + row_in;
      a[mi] = *(const bf16x8*)(&ldsA[buf][0] + row * 32 + kgrp * 8);
    }
    #pragma unroll
    for (int ni = 0; ni < 4; ++ni) {
      int row = wc * 64 + ni * 16 + row_in;
      b[ni] = *(const bf16x8*)(&ldsB[buf][0] + row * 32 + kgrp * 8);
    }
    #pragma unroll
    for (int mi = 0; mi < 4; ++mi)
      #pragma unroll
      for (int ni = 0; ni < 4; ++ni)
        acc[mi][ni] = mfma16(a[mi], b[ni], acc[mi][ni]);
    __syncthreads();
    buf ^= 1;
  }

  #pragma unroll
  for (int ni = 0; ni < 4; ++ni) {
    int v = n0 + wc * 64 + ni * 16 + row_in;
    if (v >= V_) continue;
    float bias = bout[v];
    #pragma unroll
    for (int mi = 0; mi < 4; ++mi) {
      #pragma unroll
      for (int r = 0; r < 4; ++r) {
        int m = m0 + wr * 64 + mi * 16 + kgrp * 4 + r;
        int tt = m >> 7;
        int bb_ = m & 127;
        out[((size_t)bb_ * T_ + tt) * V_ + v] = acc[mi][ni][r] + bias;
      }
    }
  }
}

// ---------------------------------------------------------------------------
extern "C" void kernel_launch(void* const* d_in, const int* in_sizes, int n_in,
                              void* d_out, int out_size, void* d_ws, size_t ws_size,
                              hipStream_t stream) {
  const float* z     = (const float*)d_in[0];
  const int*   targ  = (const int*)d_in[1];
  const float* emb   = (const float*)d_in[2];
  const float* W_ih0 = (const float*)d_in[3];
  const float* W_hh0 = (const float*)d_in[4];
  const float* b_ih0 = (const float*)d_in[5];
  const float* b_hh0 = (const float*)d_in[6];
  const float* W_ih1 = (const float*)d_in[7];
  const float* W_hh1 = (const float*)d_in[8];
  const float* b_ih1 = (const float*)d_in[9];
  const float* b_hh1 = (const float*)d_in[10];
  const float* W_out = (const float*)d_in[11];
  const float* b_out = (const float*)d_in[12];
  const float* W_lat = (const float*)d_in[13];
  const float* b_lat = (const float*)d_in[14];
  float* out = (float*)d_out;

  char* ws = (char*)d_ws;
  __hip_bfloat16* h0hi  = (__hip_bfloat16*)(ws);              // 65*BH*2 = 4,259,840
  __hip_bfloat16* h0res = (__hip_bfloat16*)(ws + 4259840);
  __hip_bfloat16* hshi  = (__hip_bfloat16*)(ws + 8519680);
  __hip_bfloat16* hsres = (__hip_bfloat16*)(ws + 12779520);
  __hip_bfloat16* embB  = (__hip_bfloat16*)(ws + 17039360);   // 15,627,264
  __hip_bfloat16* Wih0B = (__hip_bfloat16*)(ws + 32666624);   // 524,288
  __hip_bfloat16* Whh0B = (__hip_bfloat16*)(ws + 33190912);
  __hip_bfloat16* Wih1B = (__hip_bfloat16*)(ws + 33715200);
  __hip_bfloat16* Whh1B = (__hip_bfloat16*)(ws + 34239488);
  __hip_bfloat16* WoutB = (__hip_bfloat16*)(ws + 34763776);   // 15,627,264
  int* cnt0 = (int*)(ws + 50391040);                          // 64 ints
  int* cnt1 = cnt0 + 64;

  reset_cnt<<<1, 128, 0, stream>>>(cnt0);
  conv_bf16<<<3816, 256, 0, stream>>>(emb, embB, V_ * E_);
  conv_bf16<<<128, 256, 0, stream>>>(W_ih0, Wih0B, 1024 * 256);
  conv_bf16<<<128, 256, 0, stream>>>(W_hh0, Whh0B, 1024 * 256);
  conv_bf16<<<128, 256, 0, stream>>>(W_ih1, Wih1B, 1024 * 256);
  conv_bf16<<<128, 256, 0, stream>>>(W_hh1, Whh1B, 1024 * 256);
  conv_bf16<<<3816, 256, 0, stream>>>(W_out, WoutB, V_ * H_);
  init_kernel<<<128, 256, 0, stream>>>(z, W_lat, b_lat, h0hi, h0res, hshi, hsres);

  lstm_persist<<<32, 256, 0, stream>>>(
      targ, embB,
      Wih0B, Whh0B, b_ih0, b_hh0,
      Wih1B, Whh1B, b_ih1, b_hh1,
      h0hi, h0res, hshi, hsres, cnt0, cnt1);

  {
    dim3 g(64, 239);
    gemm_out<<<g, 256, 0, stream>>>(hshi + BH_, WoutB, b_out, out);
  }
}

// Round 9
// 1424.843 us; speedup vs baseline: 3.0490x; 1.0819x over previous
//
#include <hip/hip_runtime.h>
#include <hip/hip_bf16.h>

#define B_ 128
#define T_ 64
#define H_ 256
#define E_ 256
#define L_ 512
#define V_ 30522
#define EOS_ 2
#define BH_ (B_ * H_)

typedef __attribute__((ext_vector_type(8))) short bf16x8;
typedef __attribute__((ext_vector_type(4))) float f32x4;

__device__ __forceinline__ float4 ld4(const float* p) { return *(const float4*)p; }
__device__ __forceinline__ float dot4(float4 a, float4 b) {
  return a.x * b.x + a.y * b.y + a.z * b.z + a.w * b.w;
}
__device__ __forceinline__ float sigf(float x) {
  return __builtin_amdgcn_rcpf(1.f + __expf(-x));
}
__device__ __forceinline__ float tanh_fast(float x) {
  float e = __expf(2.f * x);
  return 1.f - 2.f * __builtin_amdgcn_rcpf(e + 1.f);
}
__device__ __forceinline__ f32x4 mfma16(bf16x8 a, bf16x8 b, f32x4 c) {
  return __builtin_amdgcn_mfma_f32_16x16x32_bf16(a, b, c, 0, 0, 0);
}

// ---------------------------------------------------------------------------
// generic f32 -> bf16 convert (total % 8 == 0)
// ---------------------------------------------------------------------------
__global__ __launch_bounds__(256) void conv_bf16(
    const float* __restrict__ src, __hip_bfloat16* __restrict__ dst, int total) {
  int i = (blockIdx.x * 256 + threadIdx.x) * 8;
  if (i + 8 <= total) {
    float4 lo = ld4(src + i), hi = ld4(src + i + 4);
    union { bf16x8 v8; __hip_bfloat16 e[8]; } u;
    u.e[0] = __float2bfloat16(lo.x); u.e[1] = __float2bfloat16(lo.y);
    u.e[2] = __float2bfloat16(lo.z); u.e[3] = __float2bfloat16(lo.w);
    u.e[4] = __float2bfloat16(hi.x); u.e[5] = __float2bfloat16(hi.y);
    u.e[6] = __float2bfloat16(hi.z); u.e[7] = __float2bfloat16(hi.w);
    *(bf16x8*)(dst + i) = u.v8;
  }
}

__global__ void reset_cnt(int* __restrict__ c) { c[threadIdx.x] = 0; }

// ---------------------------------------------------------------------------
// init: h_init = z @ W_lat^T + b_lat -> slot 0 of h0 & hs (hi+res)
// ---------------------------------------------------------------------------
__global__ __launch_bounds__(256) void init_kernel(
    const float* __restrict__ z, const float* __restrict__ W_lat,
    const float* __restrict__ b_lat,
    __hip_bfloat16* __restrict__ h0hi, __hip_bfloat16* __restrict__ h0res,
    __hip_bfloat16* __restrict__ hshi, __hip_bfloat16* __restrict__ hsres) {
  int b = blockIdx.x;
  int h = threadIdx.x;
  const float* zr = z + (size_t)b * L_;
  const float* wr = W_lat + (size_t)h * L_;
  float acc = b_lat[h];
  #pragma unroll 4
  for (int l = 0; l < L_; l += 4) acc += dot4(ld4(zr + l), ld4(wr + l));
  __hip_bfloat16 hi = __float2bfloat16(acc);
  __hip_bfloat16 re = __float2bfloat16(acc - __bfloat162float(hi));
  int idx = b * H_ + h;
  h0hi[idx] = hi; h0res[idx] = re;
  hshi[idx] = hi; hsres[idx] = re;
}

// ---------------------------------------------------------------------------
// Persistent MFMA recurrence, regular launch (32 blocks), flag sync WITHOUT
// acquire-invalidate. Safety argument:
//  - consumers only read addresses never touched before by their CU/XCD
//    (history slots are write-once/read-once, monotonically advancing), so
//    no stale L1/L2 copy can exist below the IC for the data path;
//  - producers push dirty lines to the IC with an agent release fence
//    (buffer_wbl2) BEFORE the relaxed flag increment (RMW executes at IC);
//  - consumers poll with a relaxed agent RMW (fetch_add 0), which cannot
//    hit a stale cached flag, then __syncthreads() orders the data loads.
// => no L2 invalidation anywhere: weights stay L2-resident all 64 steps.
// ---------------------------------------------------------------------------
__device__ __forceinline__ void wait_cnt(int* p) {
  if (threadIdx.x == 0) {
    int it = 0;
    while (__hip_atomic_fetch_add(p, 0, __ATOMIC_RELAXED,
                                  __HIP_MEMORY_SCOPE_AGENT) < 16 &&
           it < (1 << 19)) {
      __builtin_amdgcn_s_sleep(1);
      ++it;
    }
  }
  __syncthreads();   // exec+mem barrier: data loads cannot hoist above
}

__device__ __forceinline__ void signal_cnt(int* p) {
  __syncthreads();               // all waves' stores vmcnt-drained
  if (threadIdx.x == 0) {
    __threadfence();             // agent fence: wbL2 -> IC, waits completion
    __hip_atomic_fetch_add(p, 1, __ATOMIC_RELAXED, __HIP_MEMORY_SCOPE_AGENT);
  }
}

__global__ __launch_bounds__(256, 1) void lstm_persist(
    const int* __restrict__ targ, const __hip_bfloat16* __restrict__ embB,
    const __hip_bfloat16* __restrict__ Wih0B, const __hip_bfloat16* __restrict__ Whh0B,
    const float* __restrict__ b_ih0, const float* __restrict__ b_hh0,
    const __hip_bfloat16* __restrict__ Wih1B, const __hip_bfloat16* __restrict__ Whh1B,
    const float* __restrict__ b_ih1, const float* __restrict__ b_hh1,
    __hip_bfloat16* __restrict__ h0hi, __hip_bfloat16* __restrict__ h0res,
    __hip_bfloat16* __restrict__ hshi, __hip_bfloat16* __restrict__ hsres,
    int* __restrict__ cnt0, int* __restrict__ cnt1) {
  const int blk = blockIdx.x;
  const bool isL0 = blk < 16;
  const int chunk = isL0 ? blk : blk - 16;
  const int tid = threadIdx.x;
  const int lane = tid & 63;
  const int wave = tid >> 6;
  const int col = lane & 15;
  const int klo = lane >> 4;
  const int mbase = wave * 32;
  const int hcol = chunk * 16 + col;

  const float* bi = isL0 ? b_ih0 : b_ih1;
  const float* bh = isL0 ? b_hh0 : b_hh1;
  float bias[4];
  #pragma unroll
  for (int g = 0; g < 4; ++g) bias[g] = bi[g * 256 + hcol] + bh[g * 256 + hcol];

  // weight-stationary (compiler may remat some loads; they stay L2-hot now)
  const __hip_bfloat16* W1 = isL0 ? Wih0B : Wih1B;
  const __hip_bfloat16* W2 = isL0 ? Whh0B : Whh1B;
  bf16x8 bw1[4][8], bw2[4][8];
  #pragma unroll
  for (int g = 0; g < 4; ++g) {
    int row = g * 256 + hcol;
    #pragma unroll
    for (int ks = 0; ks < 8; ++ks) {
      bw1[g][ks] = *(const bf16x8*)(W1 + (size_t)row * 256 + ks * 32 + klo * 8);
      bw2[g][ks] = *(const bf16x8*)(W2 + (size_t)row * 256 + ks * 32 + klo * 8);
    }
  }

  const int b0 = mbase + col;
  const int b1 = mbase + 16 + col;
  f32x4 cst[2];
  cst[0] = (f32x4){0.f, 0.f, 0.f, 0.f};
  cst[1] = (f32x4){0.f, 0.f, 0.f, 0.f};

  for (int t = 0; t < T_; ++t) {
    if (isL0) {
      if (t) wait_cnt(cnt0 + t - 1);            // h0 slot t complete
    } else {
      wait_cnt(cnt0 + t);                       // h0 slot t+1 complete
      if (t) wait_cnt(cnt1 + t - 1);            // hs slot t complete
    }

    f32x4 acc[2][4];
    #pragma unroll
    for (int mt = 0; mt < 2; ++mt)
      #pragma unroll
      for (int g = 0; g < 4; ++g) acc[mt][g] = (f32x4){0.f, 0.f, 0.f, 0.f};

    if (isL0) {
      int tok0 = (t == 0) ? EOS_ : targ[b0 * T_ + t - 1];
      int tok1 = (t == 0) ? EOS_ : targ[b1 * T_ + t - 1];
      const __hip_bfloat16* x0 = embB + (size_t)tok0 * E_;
      const __hip_bfloat16* x1 = embB + (size_t)tok1 * E_;
      const __hip_bfloat16* hh0 = h0hi + (size_t)t * BH_ + b0 * H_;
      const __hip_bfloat16* hh1 = h0hi + (size_t)t * BH_ + b1 * H_;
      const __hip_bfloat16* hr0 = h0res + (size_t)t * BH_ + b0 * H_;
      const __hip_bfloat16* hr1 = h0res + (size_t)t * BH_ + b1 * H_;
      #pragma unroll
      for (int ks = 0; ks < 8; ++ks) {
        const int ko = ks * 32 + klo * 8;
        bf16x8 ax0 = *(const bf16x8*)(x0 + ko);
        bf16x8 ax1 = *(const bf16x8*)(x1 + ko);
        bf16x8 ahh0 = *(const bf16x8*)(hh0 + ko);
        bf16x8 ahh1 = *(const bf16x8*)(hh1 + ko);
        bf16x8 ahr0 = *(const bf16x8*)(hr0 + ko);
        bf16x8 ahr1 = *(const bf16x8*)(hr1 + ko);
        #pragma unroll
        for (int g = 0; g < 4; ++g) {
          acc[0][g] = mfma16(ax0, bw1[g][ks], acc[0][g]);
          acc[1][g] = mfma16(ax1, bw1[g][ks], acc[1][g]);
          acc[0][g] = mfma16(ahh0, bw2[g][ks], acc[0][g]);
          acc[1][g] = mfma16(ahh1, bw2[g][ks], acc[1][g]);
          acc[0][g] = mfma16(ahr0, bw2[g][ks], acc[0][g]);
          acc[1][g] = mfma16(ahr1, bw2[g][ks], acc[1][g]);
        }
      }
    } else {
      const __hip_bfloat16* xh0 = h0hi + (size_t)(t + 1) * BH_ + b0 * H_;
      const __hip_bfloat16* xh1 = h0hi + (size_t)(t + 1) * BH_ + b1 * H_;
      const __hip_bfloat16* xr0 = h0res + (size_t)(t + 1) * BH_ + b0 * H_;
      const __hip_bfloat16* xr1 = h0res + (size_t)(t + 1) * BH_ + b1 * H_;
      const __hip_bfloat16* hh0 = hshi + (size_t)t * BH_ + b0 * H_;
      const __hip_bfloat16* hh1 = hshi + (size_t)t * BH_ + b1 * H_;
      const __hip_bfloat16* hr0 = hsres + (size_t)t * BH_ + b0 * H_;
      const __hip_bfloat16* hr1 = hsres + (size_t)t * BH_ + b1 * H_;
      #pragma unroll
      for (int ks = 0; ks < 8; ++ks) {
        const int ko = ks * 32 + klo * 8;
        bf16x8 axh0 = *(const bf16x8*)(xh0 + ko);
        bf16x8 axh1 = *(const bf16x8*)(xh1 + ko);
        bf16x8 axr0 = *(const bf16x8*)(xr0 + ko);
        bf16x8 axr1 = *(const bf16x8*)(xr1 + ko);
        bf16x8 ahh0 = *(const bf16x8*)(hh0 + ko);
        bf16x8 ahh1 = *(const bf16x8*)(hh1 + ko);
        bf16x8 ahr0 = *(const bf16x8*)(hr0 + ko);
        bf16x8 ahr1 = *(const bf16x8*)(hr1 + ko);
        #pragma unroll
        for (int g = 0; g < 4; ++g) {
          acc[0][g] = mfma16(axh0, bw1[g][ks], acc[0][g]);
          acc[1][g] = mfma16(axh1, bw1[g][ks], acc[1][g]);
          acc[0][g] = mfma16(axr0, bw1[g][ks], acc[0][g]);
          acc[1][g] = mfma16(axr1, bw1[g][ks], acc[1][g]);
          acc[0][g] = mfma16(ahh0, bw2[g][ks], acc[0][g]);
          acc[1][g] = mfma16(ahh1, bw2[g][ks], acc[1][g]);
          acc[0][g] = mfma16(ahr0, bw2[g][ks], acc[0][g]);
          acc[1][g] = mfma16(ahr1, bw2[g][ks], acc[1][g]);
        }
      }
    }

    // epilogue: gates -> h, write slot t+1 (hi/res), c stays in regs
    __hip_bfloat16* whi = (isL0 ? h0hi : hshi) + (size_t)(t + 1) * BH_;
    __hip_bfloat16* wre = (isL0 ? h0res : hsres) + (size_t)(t + 1) * BH_;
    #pragma unroll
    for (int mt = 0; mt < 2; ++mt) {
      #pragma unroll
      for (int r = 0; r < 4; ++r) {
        float iv = sigf(acc[mt][0][r] + bias[0]);
        float fv = sigf(acc[mt][1][r] + bias[1]);
        float gv = tanh_fast(acc[mt][2][r] + bias[2]);
        float ov = sigf(acc[mt][3][r] + bias[3]);
        float c = fv * cst[mt][r] + iv * gv;
        cst[mt][r] = c;
        float h = ov * tanh_fast(c);
        __hip_bfloat16 hi = __float2bfloat16(h);
        __hip_bfloat16 re = __float2bfloat16(h - __bfloat162float(hi));
        int brow = mbase + mt * 16 + klo * 4 + r;
        whi[(size_t)brow * H_ + hcol] = hi;
        wre[(size_t)brow * H_ + hcol] = re;
      }
    }
    signal_cnt((isL0 ? cnt0 : cnt1) + t);
  }
}

// ---------------------------------------------------------------------------
// logits = hs @ WoutBf^T + b_out.  128x128 tile, BK=32, double-buffered
// global_load_lds staging, LDS frag reads. Output [B][T][V] f32. (unchanged)
// ---------------------------------------------------------------------------
__global__ __launch_bounds__(256) void gemm_out(
    const __hip_bfloat16* __restrict__ hs,
    const __hip_bfloat16* __restrict__ Wb, const float* __restrict__ bout,
    float* __restrict__ out) {
  __shared__ __hip_bfloat16 ldsA[2][128 * 32];
  __shared__ __hip_bfloat16 ldsB[2][128 * 32];

  const int tid = threadIdx.x;
  const int lane = tid & 63;
  const int wave = tid >> 6;
  const int wr = wave >> 1, wc = wave & 1;
  const int m0 = blockIdx.x * 128;
  const int n0 = blockIdx.y * 128;
  const int row_in = lane & 15;
  const int kgrp = lane >> 4;

  auto stage = [&](int kb, int buf) {
    #pragma unroll
    for (int p = 0; p < 2; ++p) {
      int slot = p * 256 + wave * 64 + lane;
      int row = slot >> 2;
      int k16 = slot & 3;
      const __hip_bfloat16* srcA = hs + (size_t)(m0 + row) * H_ + kb * 32 + k16 * 8;
      int rn = n0 + row; if (rn >= V_) rn = V_ - 1;
      const __hip_bfloat16* srcB = Wb + (size_t)rn * H_ + kb * 32 + k16 * 8;
      __hip_bfloat16* dstA = &ldsA[buf][0] + (p * 2048 + wave * 512);
      __hip_bfloat16* dstB = &ldsB[buf][0] + (p * 2048 + wave * 512);
      __builtin_amdgcn_global_load_lds(
          (const __attribute__((address_space(1))) unsigned int*)srcA,
          (__attribute__((address_space(3))) unsigned int*)dstA, 16, 0, 0);
      __builtin_amdgcn_global_load_lds(
          (const __attribute__((address_space(1))) unsigned int*)srcB,
          (__attribute__((address_space(3))) unsigned int*)dstB, 16, 0, 0);
    }
  };

  f32x4 acc[4][4];
  #pragma unroll
  for (int i = 0; i < 4; ++i)
    #pragma unroll
    for (int j = 0; j < 4; ++j) acc[i][j] = (f32x4){0.f, 0.f, 0.f, 0.f};

  stage(0, 0);
  __syncthreads();

  int buf = 0;
  for (int kb = 0; kb < 8; ++kb) {
    if (kb < 7) stage(kb + 1, buf ^ 1);
    bf16x8 a[4], b[4];
    #pragma unroll
    for (int mi = 0; mi < 4; ++mi) {
      int row = wr * 64 + mi * 16 + row_in;
      a[mi] = *(const bf16x8*)(&ldsA[buf][0] + row * 32 + kgrp * 8);
    }
    #pragma unroll
    for (int ni = 0; ni < 4; ++ni) {
      int row = wc * 64 + ni * 16 + row_in;
      b[ni] = *(const bf16x8*)(&ldsB[buf][0] + row * 32 + kgrp * 8);
    }
    #pragma unroll
    for (int mi = 0; mi < 4; ++mi)
      #pragma unroll
      for (int ni = 0; ni < 4; ++ni)
        acc[mi][ni] = mfma16(a[mi], b[ni], acc[mi][ni]);
    __syncthreads();
    buf ^= 1;
  }

  #pragma unroll
  for (int ni = 0; ni < 4; ++ni) {
    int v = n0 + wc * 64 + ni * 16 + row_in;
    if (v >= V_) continue;
    float bias = bout[v];
    #pragma unroll
    for (int mi = 0; mi < 4; ++mi) {
      #pragma unroll
      for (int r = 0; r < 4; ++r) {
        int m = m0 + wr * 64 + mi * 16 + kgrp * 4 + r;
        int tt = m >> 7;
        int bb_ = m & 127;
        out[((size_t)bb_ * T_ + tt) * V_ + v] = acc[mi][ni][r] + bias;
      }
    }
  }
}

// ---------------------------------------------------------------------------
extern "C" void kernel_launch(void* const* d_in, const int* in_sizes, int n_in,
                              void* d_out, int out_size, void* d_ws, size_t ws_size,
                              hipStream_t stream) {
  const float* z     = (const float*)d_in[0];
  const int*   targ  = (const int*)d_in[1];
  const float* emb   = (const float*)d_in[2];
  const float* W_ih0 = (const float*)d_in[3];
  const float* W_hh0 = (const float*)d_in[4];
  const float* b_ih0 = (const float*)d_in[5];
  const float* b_hh0 = (const float*)d_in[6];
  const float* W_ih1 = (const float*)d_in[7];
  const float* W_hh1 = (const float*)d_in[8];
  const float* b_ih1 = (const float*)d_in[9];
  const float* b_hh1 = (const float*)d_in[10];
  const float* W_out = (const float*)d_in[11];
  const float* b_out = (const float*)d_in[12];
  const float* W_lat = (const float*)d_in[13];
  const float* b_lat = (const float*)d_in[14];
  float* out = (float*)d_out;

  char* ws = (char*)d_ws;
  __hip_bfloat16* h0hi  = (__hip_bfloat16*)(ws);              // 65*BH*2 = 4,259,840
  __hip_bfloat16* h0res = (__hip_bfloat16*)(ws + 4259840);
  __hip_bfloat16* hshi  = (__hip_bfloat16*)(ws + 8519680);
  __hip_bfloat16* hsres = (__hip_bfloat16*)(ws + 12779520);
  __hip_bfloat16* embB  = (__hip_bfloat16*)(ws + 17039360);   // 15,627,264
  __hip_bfloat16* Wih0B = (__hip_bfloat16*)(ws + 32666624);   // 524,288
  __hip_bfloat16* Whh0B = (__hip_bfloat16*)(ws + 33190912);
  __hip_bfloat16* Wih1B = (__hip_bfloat16*)(ws + 33715200);
  __hip_bfloat16* Whh1B = (__hip_bfloat16*)(ws + 34239488);
  __hip_bfloat16* WoutB = (__hip_bfloat16*)(ws + 34763776);   // 15,627,264
  int* cnt0 = (int*)(ws + 50391040);                          // 64 ints
  int* cnt1 = cnt0 + 64;

  reset_cnt<<<1, 128, 0, stream>>>(cnt0);
  conv_bf16<<<3816, 256, 0, stream>>>(emb, embB, V_ * E_);
  conv_bf16<<<128, 256, 0, stream>>>(W_ih0, Wih0B, 1024 * 256);
  conv_bf16<<<128, 256, 0, stream>>>(W_hh0, Whh0B, 1024 * 256);
  conv_bf16<<<128, 256, 0, stream>>>(W_ih1, Wih1B, 1024 * 256);
  conv_bf16<<<128, 256, 0, stream>>>(W_hh1, Whh1B, 1024 * 256);
  conv_bf16<<<3816, 256, 0, stream>>>(W_out, WoutB, V_ * H_);
  init_kernel<<<128, 256, 0, stream>>>(z, W_lat, b_lat, h0hi, h0res, hshi, hsres);

  lstm_persist<<<32, 256, 0, stream>>>(
      targ, embB,
      Wih0B, Whh0B, b_ih0, b_hh0,
      Wih1B, Whh1B, b_ih1, b_hh1,
      h0hi, h0res, hshi, hsres, cnt0, cnt1);

  {
    dim3 g(64, 239);
    gemm_out<<<g, 256, 0, stream>>>(hshi + BH_, WoutB, b_out, out);
  }
}